// Round 1
// baseline (2477.821 us; speedup 1.0000x reference)
//
#include <hip/hip_runtime.h>
#include <math.h>

#define N_NODES 49152
#define BGRAPH  64
#define MAXN_   768
#define NEDGE   491520
#define DD      128
#define CC      160
#define DI_     320
#define DS_     128
#define DTR_    10

__device__ __forceinline__ float sigm(float x) { return 1.f / (1.f + __expf(-x)); }
__device__ __forceinline__ float softplusf(float x) {
    return (x > 20.f) ? x : log1pf(__expf(x));
}

// block-wide sum: all threads get result. blockDim multiple of 64.
__device__ __forceinline__ float blkSum(float v, float* scratch) {
    __syncthreads();
    #pragma unroll
    for (int off = 32; off > 0; off >>= 1) v += __shfl_down(v, off);
    if ((threadIdx.x & 63) == 0) scratch[threadIdx.x >> 6] = v;
    __syncthreads();
    int nw = blockDim.x >> 6;
    float s = 0.f;
    for (int i = 0; i < nw; ++i) s += scratch[i];
    return s;
}

__device__ __forceinline__ float blkMax(float v, float* scratch) {
    __syncthreads();
    #pragma unroll
    for (int off = 32; off > 0; off >>= 1) v = fmaxf(v, __shfl_down(v, off));
    if ((threadIdx.x & 63) == 0) scratch[threadIdx.x >> 6] = v;
    __syncthreads();
    int nw = blockDim.x >> 6;
    float s = scratch[0];
    for (int i = 1; i < nw; ++i) s = fmaxf(s, scratch[i]);
    return s;
}

// ---------------- K2: edge gather + gated scatter-add (3 scales) ----------------
__global__ void k_edge(const float* __restrict__ x, const float* __restrict__ ea,
                       const int* __restrict__ src, const int* __restrict__ dst,
                       const float* __restrict__ We, const float* __restrict__ be,
                       float* __restrict__ agg)
{
    int tid = threadIdx.x;
    int sub = tid >> 7;        // 2 edges per 256-block
    int d   = tid & 127;
    int e   = blockIdx.x * 2 + sub;
    if (e >= NEDGE) return;
    int s  = src[e];
    int dn = dst[e];
    float ea0 = ea[e * 2], ea1 = ea[e * 2 + 1];
    float xv = x[s * DD + d];
    #pragma unroll
    for (int i = 0; i < 3; ++i) {
        float w0 = We[i * 256 + d];
        float w1 = We[i * 256 + 128 + d];
        float bb = be[i * 128 + d];
        float g = sigm(ea0 * w0 + ea1 * w1 + bb);
        atomicAdd(&agg[i * (N_NODES * DD) + dn * DD + d], xv * g);
    }
}

// ---------------- K3: xs_i = relu((x+agg_i)@Wx_i + bx_i), in-place over agg ----
__global__ void k_xs(const float* __restrict__ x, float* __restrict__ agg,
                     const float* __restrict__ Wx, const float* __restrict__ bx)
{
    const int i  = blockIdx.y;
    const int n0 = blockIdx.x * 16;
    const int j  = threadIdx.x;  // 128
    __shared__ float inL[16 * 128];
    float* aggi = agg + i * (N_NODES * DD);
    #pragma unroll
    for (int r = 0; r < 16; ++r)
        inL[r * 128 + j] = x[(n0 + r) * DD + j] + aggi[(n0 + r) * DD + j];
    __syncthreads();
    float acc[16];
    #pragma unroll
    for (int r = 0; r < 16; ++r) acc[r] = 0.f;
    const float* W = Wx + i * (DD * DD);
    for (int k = 0; k < 128; ++k) {
        float w = W[k * 128 + j];
        #pragma unroll
        for (int r = 0; r < 16; ++r) acc[r] += inL[r * 128 + k] * w;
    }
    float bb = bx[i * 128 + j];
    #pragma unroll
    for (int r = 0; r < 16; ++r) {
        float v = acc[r] + bb;
        aggi[(n0 + r) * DD + j] = v > 0.f ? v : 0.f;
    }
}

// ---------------- K4: P0 = xp @ wm_w0[:160] + b0  (step-invariant) ------------
__global__ void k_p0(const float* __restrict__ x, const float* __restrict__ lpe,
                     const float* __restrict__ rwse, const float* __restrict__ w0,
                     const float* __restrict__ b0, float* __restrict__ P0)
{
    const int n0 = blockIdx.x * 16;
    const int j  = threadIdx.x;  // 192
    __shared__ float inL[16 * 160];
    for (int idx = j; idx < 16 * 160; idx += 192) {
        int r = idx / 160, k = idx - r * 160;
        int n = n0 + r;
        float v;
        if (k < 128)      v = x[n * 128 + k];
        else if (k < 144) v = lpe[n * 16 + (k - 128)];
        else              v = rwse[n * 16 + (k - 144)];
        inL[idx] = v;
    }
    __syncthreads();
    if (j < 160) {
        float acc[16];
        #pragma unroll
        for (int r = 0; r < 16; ++r) acc[r] = 0.f;
        for (int k = 0; k < 160; ++k) {
            float w = w0[k * 160 + j];
            #pragma unroll
            for (int r = 0; r < 16; ++r) acc[r] += inL[r * 160 + k] * w;
        }
        float bb = b0[j];
        #pragma unroll
        for (int r = 0; r < 16; ++r) P0[(n0 + r) * 160 + j] = acc[r] + bb;
    }
}

// ---------------- K6: per-row MLP -> attention scores -------------------------
__global__ void k_mlp(const float* __restrict__ P0, const float* __restrict__ hw0,
                      const float* __restrict__ w1, const float* __restrict__ b1,
                      const float* __restrict__ w2, const float* __restrict__ b2,
                      const float* __restrict__ w3, const float* __restrict__ b3,
                      float* __restrict__ scores)
{
    const int n0 = blockIdx.x * 16;
    const int b  = n0 / MAXN_;      // 16 | 768, so uniform per block
    const int j  = threadIdx.x;     // 192
    __shared__ float bufA[16 * 160];
    __shared__ float bufB[16 * 160];
    __shared__ float red[192];
    // a1 = relu(P0 + hw0[b])
    for (int idx = j; idx < 16 * 160; idx += 192) {
        int r = idx / 160, k = idx - r * 160;
        float v = P0[(n0 + r) * 160 + k] + hw0[b * 160 + k];
        bufA[idx] = v > 0.f ? v : 0.f;
    }
    __syncthreads();
    if (j < 160) {  // a2 = relu(a1@w1+b1)
        float acc[16];
        #pragma unroll
        for (int r = 0; r < 16; ++r) acc[r] = 0.f;
        for (int k = 0; k < 160; ++k) {
            float w = w1[k * 160 + j];
            #pragma unroll
            for (int r = 0; r < 16; ++r) acc[r] += bufA[r * 160 + k] * w;
        }
        float bb = b1[j];
        #pragma unroll
        for (int r = 0; r < 16; ++r) {
            float v = acc[r] + bb;
            bufB[r * 160 + j] = v > 0.f ? v : 0.f;
        }
    }
    __syncthreads();
    if (j < 160) {  // a3 = relu(a2@w2+b2)
        float acc[16];
        #pragma unroll
        for (int r = 0; r < 16; ++r) acc[r] = 0.f;
        for (int k = 0; k < 160; ++k) {
            float w = w2[k * 160 + j];
            #pragma unroll
            for (int r = 0; r < 16; ++r) acc[r] += bufB[r * 160 + k] * w;
        }
        float bb = b2[j];
        #pragma unroll
        for (int r = 0; r < 16; ++r) {
            float v = acc[r] + bb;
            bufA[r * 160 + j] = v > 0.f ? v : 0.f;
        }
    }
    __syncthreads();
    {   // score = a3 . w3 + b3
        int r = j / 12, lane = j - r * 12;   // 16 rows x 12 threads
        float p = 0.f;
        for (int k = lane; k < 160; k += 12) p += bufA[r * 160 + k] * w3[k];
        red[j] = p;
    }
    __syncthreads();
    if (j < 16) {
        float s = 0.f;
        #pragma unroll
        for (int i = 0; i < 12; ++i) s += red[j * 12 + i];
        scores[n0 + j] = s + b3[0];
    }
}

// ---------------- K7: per-graph softmax + t + GRU + hw0_next ------------------
__global__ void k_graph(const float* __restrict__ scores,
                        const float* __restrict__ x, const float* __restrict__ lpe,
                        const float* __restrict__ rwse,
                        const float* __restrict__ Wi, const float* __restrict__ Wh,
                        const float* __restrict__ bi, const float* __restrict__ bh,
                        const float* __restrict__ w0h,
                        float* __restrict__ h, float* __restrict__ hw0,
                        float* __restrict__ tok, int step)
{
    const int b   = blockIdx.x;
    const int tid = threadIdx.x;  // 256
    __shared__ float eL[MAXN_];
    __shared__ float tL[160];
    __shared__ float hL[160];
    __shared__ float hN[160];
    __shared__ float red[8];
    const float inv_sqrt_d = 0.08838834764831845f;  // 128^-0.5

    float m = -1e30f;
    for (int i = tid; i < MAXN_; i += 256) {
        float q = scores[b * MAXN_ + i] * inv_sqrt_d;
        eL[i] = q;
        m = fmaxf(m, q);
    }
    m = blkMax(m, red);
    float s = 0.f;
    for (int i = tid; i < MAXN_; i += 256) {
        float e = __expf(eL[i] - m);
        eL[i] = e;
        s += e;
    }
    if (tid < 160) hL[tid] = h[b * 160 + tid];
    float S = blkSum(s, red);
    float scale = 1.f / (S * (float)MAXN_);
    // t = sum_i alpha_i * xp_i / MAXN
    if (tid < 160) {
        const int c = tid;
        float acc = 0.f;
        for (int i = 0; i < MAXN_; ++i) {
            int n = b * MAXN_ + i;
            float v;
            if (c < 128)      v = x[n * 128 + c];
            else if (c < 144) v = lpe[n * 16 + (c - 128)];
            else              v = rwse[n * 16 + (c - 144)];
            acc += eL[i] * v;
        }
        float tv = acc * scale;
        tL[c] = tv;
        tok[b * 640 + step * 160 + c] = tv;
    }
    __syncthreads();
    // GRU
    if (tid < 160) {
        const int c = tid;
        float gr = bi[c], gz = bi[160 + c], gn = bi[320 + c];
        float hr = bh[c], hz = bh[160 + c], hn = bh[320 + c];
        for (int k = 0; k < 160; ++k) {
            float tv = tL[k], hv = hL[k];
            gr += tv * Wi[k * 480 + c];
            gz += tv * Wi[k * 480 + 160 + c];
            gn += tv * Wi[k * 480 + 320 + c];
            hr += hv * Wh[k * 480 + c];
            hz += hv * Wh[k * 480 + 160 + c];
            hn += hv * Wh[k * 480 + 320 + c];
        }
        float r = sigm(gr + hr);
        float z = sigm(gz + hz);
        float n = tanhf(gn + r * hn);
        float hnew = (1.f - z) * n + z * hL[c];
        hN[c] = hnew;
        h[b * 160 + c] = hnew;
    }
    __syncthreads();
    // hw0_next = h_new @ wm_w0[160:,:]
    if (tid < 160) {
        const int j = tid;
        float acc = 0.f;
        for (int k = 0; k < 160; ++k) acc += hN[k] * w0h[k * 160 + j];
        hw0[b * 160 + j] = acc;
    }
}

// ---------------- K9: mamba-ish part, one block per graph, t=3 output only ----
__global__ void k_mamba(const float* __restrict__ tok,
                        const float* __restrict__ Win, const float* __restrict__ convw,
                        const float* __restrict__ convb,
                        const float* __restrict__ Wx, const float* __restrict__ Wdt,
                        const float* __restrict__ bdt,
                        const float* __restrict__ Alog, const float* __restrict__ Dp,
                        const float* __restrict__ Wout,
                        const float* __restrict__ lng, const float* __restrict__ lnb,
                        float* __restrict__ mo_last)
{
    const int b   = blockIdx.x;
    const int tid = threadIdx.x;  // 256
    __shared__ float tokL[640];
    __shared__ float xpre[1280];
    __shared__ float xmL[1280];
    __shared__ float z3L[320];
    __shared__ float dtrL[40];
    __shared__ float BmL[512];
    __shared__ float Cm3L[128];
    __shared__ float dtL[1280];
    __shared__ float y3L[320];
    __shared__ float moL[160];
    __shared__ float red[8];

    for (int i = tid; i < 640; i += 256) tokL[i] = tok[b * 640 + i];
    __syncthreads();
    // xm_pre = tok @ Win[:, :320] ; z3 = tok[3] @ Win[:, 320:]
    for (int o = tid; o < 1280; o += 256) {
        int t = o / 320, d = o - t * 320;
        float acc = 0.f;
        for (int k = 0; k < 160; ++k) acc += tokL[t * 160 + k] * Win[k * 640 + d];
        xpre[o] = acc;
    }
    for (int d = tid; d < 320; d += 256) {
        float acc = 0.f;
        for (int k = 0; k < 160; ++k) acc += tokL[480 + k] * Win[k * 640 + 320 + d];
        z3L[d] = acc;
    }
    __syncthreads();
    // causal conv + silu
    for (int o = tid; o < 1280; o += 256) {
        int t = o / 320, d = o - t * 320;
        float acc = convb[d];
        #pragma unroll
        for (int k = 0; k < 4; ++k) {
            int tt = t + k - 3;
            if (tt >= 0) acc += xpre[tt * 320 + d] * convw[d * 4 + k];
        }
        xmL[o] = acc * sigm(acc);
    }
    __syncthreads();
    // dbl = xm @ Wx : dtr(4x10), Bm(4x128), Cm(t=3 only, 128)
    for (int o = tid; o < 680; o += 256) {
        int t, col;
        if (o < 40)       { t = o / 10; col = o - t * 10; }
        else if (o < 552) { int i = o - 40; t = i >> 7; col = 10 + (i & 127); }
        else              { t = 3; col = 138 + (o - 552); }
        float acc = 0.f;
        for (int k = 0; k < 320; ++k) acc += xmL[t * 320 + k] * Wx[k * 266 + col];
        if (o < 40)       dtrL[o] = acc;
        else if (o < 552) BmL[o - 40] = acc;
        else              Cm3L[o - 552] = acc;
    }
    __syncthreads();
    // dt = softplus(dtr @ Wdt + bdt)
    for (int o = tid; o < 1280; o += 256) {
        int t = o / 320, d = o - t * 320;
        float acc = bdt[d];
        #pragma unroll
        for (int r = 0; r < 10; ++r) acc += dtrL[t * 10 + r] * Wdt[r * 320 + d];
        dtL[o] = softplusf(acc);
    }
    __syncthreads();
    // scan over T=4, keep only y at t=3; wave w handles dim d, lane handles 2 states
    {
        int w = tid >> 6, lane = tid & 63;
        for (int dbase = 0; dbase < 320; dbase += 4) {
            int d = dbase + w;
            float A0 = -__expf(Alog[d * 128 + lane]);
            float A1 = -__expf(Alog[d * 128 + 64 + lane]);
            float s0 = 0.f, s1 = 0.f;
            #pragma unroll
            for (int t = 0; t < 4; ++t) {
                float dtv = dtL[t * 320 + d];
                float xv  = xmL[t * 320 + d];
                float c0  = dtv * xv;
                s0 = s0 * __expf(dtv * A0) + c0 * BmL[t * 128 + lane];
                s1 = s1 * __expf(dtv * A1) + c0 * BmL[t * 128 + 64 + lane];
            }
            float contrib = s0 * Cm3L[lane] + s1 * Cm3L[64 + lane];
            #pragma unroll
            for (int off = 32; off > 0; off >>= 1) contrib += __shfl_down(contrib, off);
            if (lane == 0) {
                float y  = contrib + Dp[d] * xmL[3 * 320 + d];
                float zz = z3L[d];
                y3L[d] = y * (zz * sigm(zz));
            }
        }
    }
    __syncthreads();
    // mo = LN(y3 @ Wout)
    if (tid < 160) {
        float acc = 0.f;
        for (int d = 0; d < 320; ++d) acc += y3L[d] * Wout[d * 160 + tid];
        moL[tid] = acc;
    }
    float v  = (tid < 160) ? moL[tid] : 0.f;   // moL write is own-thread; blkSum barriers cover others
    float sm = blkSum(v, red);
    float sq = blkSum(v * v, red);
    float mu  = sm / 160.f;
    float var = sq / 160.f - mu * mu;
    if (tid < 160)
        mo_last[b * 160 + tid] = (moL[tid] - mu) * rsqrtf(var + 1e-5f) * lng[tid] + lnb[tid];
}

// ---------------- K10: merge MLP + two LayerNorms -> out ----------------------
__global__ void k_final(const float* __restrict__ x, const float* __restrict__ xs,
                        const int* __restrict__ batch, const float* __restrict__ mo_last,
                        const float* __restrict__ w0, const float* __restrict__ b0,
                        const float* __restrict__ g0, const float* __restrict__ beta0,
                        const float* __restrict__ w1, const float* __restrict__ b1,
                        const float* __restrict__ lng, const float* __restrict__ lnb,
                        float* __restrict__ out)
{
    const int n0 = blockIdx.x * 16;
    const int j  = threadIdx.x;  // 128
    __shared__ float catL[16 * 544];
    __shared__ float hm[16 * 128];
    __shared__ float red[4];
    for (int idx = j; idx < 16 * 544; idx += 128) {
        int r = idx / 544, c = idx - r * 544;
        int n = n0 + r;
        float v;
        if (c < 128)      v = xs[n * 128 + c];
        else if (c < 256) v = xs[N_NODES * 128 + n * 128 + (c - 128)];
        else if (c < 384) v = xs[2 * N_NODES * 128 + n * 128 + (c - 256)];
        else              v = mo_last[batch[n] * 160 + (c - 384)];
        catL[idx] = v;
    }
    __syncthreads();
    float acc[16];
    #pragma unroll
    for (int r = 0; r < 16; ++r) acc[r] = 0.f;
    for (int k = 0; k < 544; ++k) {
        float w = w0[k * 128 + j];
        #pragma unroll
        for (int r = 0; r < 16; ++r) acc[r] += catL[r * 544 + k] * w;
    }
    float b0j = b0[j], g0j = g0[j], be0j = beta0[j];
    #pragma unroll
    for (int r = 0; r < 16; ++r) hm[r * 128 + j] = acc[r] + b0j;
    // hmid = relu(LN(.)) row-wise
    for (int r = 0; r < 16; ++r) {
        float v  = hm[r * 128 + j];         // own element; blkSum barrier orders the rest
        float sm = blkSum(v, red);
        float sq = blkSum(v * v, red);
        float mu  = sm * (1.f / 128.f);
        float var = sq * (1.f / 128.f) - mu * mu;
        float nv = (v - mu) * rsqrtf(var + 1e-5f) * g0j + be0j;
        hm[r * 128 + j] = nv > 0.f ? nv : 0.f;
    }
    __syncthreads();
    float acc2[16];
    #pragma unroll
    for (int r = 0; r < 16; ++r) acc2[r] = 0.f;
    for (int k = 0; k < 128; ++k) {
        float w = w1[k * 128 + j];
        #pragma unroll
        for (int r = 0; r < 16; ++r) acc2[r] += hm[r * 128 + k] * w;
    }
    float b1j = b1[j], lgj = lng[j], lbj = lnb[j];
    for (int r = 0; r < 16; ++r) {
        float v  = acc2[r] + b1j + x[(n0 + r) * 128 + j];
        float sm = blkSum(v, red);
        float sq = blkSum(v * v, red);
        float mu  = sm * (1.f / 128.f);
        float var = sq * (1.f / 128.f) - mu * mu;
        out[(n0 + r) * 128 + j] = (v - mu) * rsqrtf(var + 1e-5f) * lgj + lbj;
    }
}

extern "C" void kernel_launch(void* const* d_in, const int* in_sizes, int n_in,
                              void* d_out, int out_size, void* d_ws, size_t ws_size,
                              hipStream_t stream) {
    const float* x     = (const float*)d_in[0];
    const float* ea    = (const float*)d_in[1];
    const float* lpe   = (const float*)d_in[2];
    const float* rwse  = (const float*)d_in[3];
    const int*   ei    = (const int*)d_in[4];
    const int*   batch = (const int*)d_in[5];
    const float* We    = (const float*)d_in[6];
    const float* be    = (const float*)d_in[7];
    const float* Wx    = (const float*)d_in[8];
    const float* bx    = (const float*)d_in[9];
    const float* w0    = (const float*)d_in[10];
    const float* b0    = (const float*)d_in[11];
    const float* w1    = (const float*)d_in[12];
    const float* b1    = (const float*)d_in[13];
    const float* w2    = (const float*)d_in[14];
    const float* b2    = (const float*)d_in[15];
    const float* w3    = (const float*)d_in[16];
    const float* b3    = (const float*)d_in[17];
    const float* gWi   = (const float*)d_in[18];
    const float* gWh   = (const float*)d_in[19];
    const float* gbi   = (const float*)d_in[20];
    const float* gbh   = (const float*)d_in[21];
    const float* mWin  = (const float*)d_in[22];
    const float* mcw   = (const float*)d_in[23];
    const float* mcb   = (const float*)d_in[24];
    const float* mWx   = (const float*)d_in[25];
    const float* mWdt  = (const float*)d_in[26];
    const float* mbdt  = (const float*)d_in[27];
    const float* mAlog = (const float*)d_in[28];
    const float* mDp   = (const float*)d_in[29];
    const float* mWout = (const float*)d_in[30];
    const float* lnmg  = (const float*)d_in[31];
    const float* lnmb  = (const float*)d_in[32];
    const float* mgw0  = (const float*)d_in[33];
    const float* mgb0  = (const float*)d_in[34];
    const float* mgg0  = (const float*)d_in[35];
    const float* mgbt0 = (const float*)d_in[36];
    const float* mgw1  = (const float*)d_in[37];
    const float* mgb1  = (const float*)d_in[38];
    const float* lng   = (const float*)d_in[39];
    const float* lnb   = (const float*)d_in[40];
    float* out = (float*)d_out;

    float* ws     = (float*)d_ws;
    float* agg    = ws;                     // 3*N*128 = 18,874,368
    float* P0     = agg + 18874368;         // N*160  =  7,864,320
    float* scores = P0 + 7864320;           // N
    float* hbuf   = scores + N_NODES;       // B*160
    float* hw0    = hbuf + 10240;           // B*160
    float* tokb   = hw0 + 10240;            // B*4*160
    float* mo     = tokb + 40960;           // B*160

    hipMemsetAsync(agg, 0, (size_t)18874368 * 4, stream);
    hipMemsetAsync(hbuf, 0, (size_t)20480 * 4, stream);  // h and hw0

    k_edge<<<NEDGE / 2, 256, 0, stream>>>(x, ea, ei, ei + NEDGE, We, be, agg);
    dim3 g3(N_NODES / 16, 3);
    k_xs<<<g3, 128, 0, stream>>>(x, agg, Wx, bx);
    k_p0<<<N_NODES / 16, 192, 0, stream>>>(x, lpe, rwse, w0, b0, P0);
    for (int t = 0; t < 4; ++t) {
        k_mlp<<<N_NODES / 16, 192, 0, stream>>>(P0, hw0, w1, b1, w2, b2, w3, b3, scores);
        k_graph<<<BGRAPH, 256, 0, stream>>>(scores, x, lpe, rwse, gWi, gWh, gbi, gbh,
                                            w0 + 160 * 160, hbuf, hw0, tokb, t);
    }
    k_mamba<<<BGRAPH, 256, 0, stream>>>(tokb, mWin, mcw, mcb, mWx, mWdt, mbdt,
                                        mAlog, mDp, mWout, lnmg, lnmb, mo);
    k_final<<<N_NODES / 16, 128, 0, stream>>>(x, agg, batch, mo, mgw0, mgb0, mgg0, mgbt0,
                                              mgw1, mgb1, lng, lnb, out);
}

// Round 2
// 2067.493 us; speedup vs baseline: 1.1985x; 1.1985x over previous
//
#include <hip/hip_runtime.h>
#include <math.h>

#define N_NODES 49152
#define BGRAPH  64
#define MAXN_   768
#define NEDGE   491520
#define DD      128
#define CC      160
#define DI_     320
#define DS_     128
#define DTR_    10

__device__ __forceinline__ float sigm(float x) { return 1.f / (1.f + __expf(-x)); }
__device__ __forceinline__ float softplusf(float x) {
    return (x > 20.f) ? x : log1pf(__expf(x));
}

// block-wide sum: all threads get result. blockDim multiple of 64.
__device__ __forceinline__ float blkSum(float v, float* scratch) {
    __syncthreads();
    #pragma unroll
    for (int off = 32; off > 0; off >>= 1) v += __shfl_down(v, off);
    if ((threadIdx.x & 63) == 0) scratch[threadIdx.x >> 6] = v;
    __syncthreads();
    int nw = blockDim.x >> 6;
    float s = 0.f;
    for (int i = 0; i < nw; ++i) s += scratch[i];
    return s;
}

__device__ __forceinline__ float blkMax(float v, float* scratch) {
    __syncthreads();
    #pragma unroll
    for (int off = 32; off > 0; off >>= 1) v = fmaxf(v, __shfl_down(v, off));
    if ((threadIdx.x & 63) == 0) scratch[threadIdx.x >> 6] = v;
    __syncthreads();
    int nw = blockDim.x >> 6;
    float s = scratch[0];
    for (int i = 1; i < nw; ++i) s = fmaxf(s, scratch[i]);
    return s;
}

// ---------------- CSR build: histogram / scan / scatter -----------------------
__global__ void k_hist(const int* __restrict__ dst, int* __restrict__ cnt) {
    int e = blockIdx.x * 256 + threadIdx.x;
    if (e < NEDGE) atomicAdd(&cnt[dst[e]], 1);
}

__global__ void k_scan(const int* __restrict__ cnt, int* __restrict__ off,
                       int* __restrict__ cursor) {
    __shared__ int part[256];
    const int t = threadIdx.x;           // 256 threads, 192 nodes each
    const int base = t * 192;
    int s = 0;
    for (int i = 0; i < 192; ++i) s += cnt[base + i];
    part[t] = s;
    __syncthreads();
    if (t == 0) {
        int run = 0;
        for (int i = 0; i < 256; ++i) { int v = part[i]; part[i] = run; run += v; }
    }
    __syncthreads();
    int run = part[t];
    for (int i = 0; i < 192; ++i) {
        int idx = base + i;
        off[idx] = run;
        cursor[idx] = run;
        run += cnt[idx];
    }
    if (t == 255) off[N_NODES] = run;    // == NEDGE
}

__global__ void k_scatter(const int* __restrict__ dst, int* __restrict__ cursor,
                          int* __restrict__ eids) {
    int e = blockIdx.x * 256 + threadIdx.x;
    if (e < NEDGE) {
        int pos = atomicAdd(&cursor[dst[e]], 1);
        eids[pos] = e;
    }
}

// ---------------- K2': gather-style gated aggregation (no atomics) ------------
__global__ void k_agg(const float* __restrict__ x, const float* __restrict__ ea,
                      const int* __restrict__ src,
                      const int* __restrict__ off, const int* __restrict__ eids,
                      const float* __restrict__ We, const float* __restrict__ be,
                      float* __restrict__ agg)
{
    const int n = blockIdx.x;
    const int d = threadIdx.x;   // 128
    const float w00 = We[d],           w01 = We[128 + d],       bb0 = be[d];
    const float w10 = We[256 + d],     w11 = We[256 + 128 + d], bb1 = be[128 + d];
    const float w20 = We[512 + d],     w21 = We[512 + 128 + d], bb2 = be[256 + d];
    const int beg = off[n], end = off[n + 1];
    float acc0 = 0.f, acc1 = 0.f, acc2 = 0.f;
    for (int i = beg; i < end; ++i) {
        int e = eids[i];
        int s = src[e];
        float ea0 = ea[2 * e], ea1 = ea[2 * e + 1];
        float xv = x[s * DD + d];
        acc0 += xv * sigm(ea0 * w00 + ea1 * w01 + bb0);
        acc1 += xv * sigm(ea0 * w10 + ea1 * w11 + bb1);
        acc2 += xv * sigm(ea0 * w20 + ea1 * w21 + bb2);
    }
    agg[              n * DD + d] = acc0;
    agg[N_NODES * DD + n * DD + d] = acc1;
    agg[2 * N_NODES * DD + n * DD + d] = acc2;
}

// ---------------- K3: xs_i = relu((x+agg_i)@Wx_i + bx_i), in-place over agg ----
__global__ void k_xs(const float* __restrict__ x, float* __restrict__ agg,
                     const float* __restrict__ Wx, const float* __restrict__ bx)
{
    const int i  = blockIdx.y;
    const int n0 = blockIdx.x * 16;
    const int j  = threadIdx.x;  // 128
    __shared__ float inL[16 * 128];
    float* aggi = agg + i * (N_NODES * DD);
    #pragma unroll
    for (int r = 0; r < 16; ++r)
        inL[r * 128 + j] = x[(n0 + r) * DD + j] + aggi[(n0 + r) * DD + j];
    __syncthreads();
    float acc[16];
    #pragma unroll
    for (int r = 0; r < 16; ++r) acc[r] = 0.f;
    const float* W = Wx + i * (DD * DD);
    for (int k = 0; k < 128; ++k) {
        float w = W[k * 128 + j];
        #pragma unroll
        for (int r = 0; r < 16; ++r) acc[r] += inL[r * 128 + k] * w;
    }
    float bb = bx[i * 128 + j];
    #pragma unroll
    for (int r = 0; r < 16; ++r) {
        float v = acc[r] + bb;
        aggi[(n0 + r) * DD + j] = v > 0.f ? v : 0.f;
    }
}

// ---------------- K4: P0 = xp @ wm_w0[:160] + b0  (step-invariant) ------------
__global__ void k_p0(const float* __restrict__ x, const float* __restrict__ lpe,
                     const float* __restrict__ rwse, const float* __restrict__ w0,
                     const float* __restrict__ b0, float* __restrict__ P0)
{
    const int n0 = blockIdx.x * 16;
    const int j  = threadIdx.x;  // 192
    __shared__ float inL[16 * 160];
    for (int idx = j; idx < 16 * 160; idx += 192) {
        int r = idx / 160, k = idx - r * 160;
        int n = n0 + r;
        float v;
        if (k < 128)      v = x[n * 128 + k];
        else if (k < 144) v = lpe[n * 16 + (k - 128)];
        else              v = rwse[n * 16 + (k - 144)];
        inL[idx] = v;
    }
    __syncthreads();
    if (j < 160) {
        float acc[16];
        #pragma unroll
        for (int r = 0; r < 16; ++r) acc[r] = 0.f;
        for (int k = 0; k < 160; ++k) {
            float w = w0[k * 160 + j];
            #pragma unroll
            for (int r = 0; r < 16; ++r) acc[r] += inL[r * 160 + k] * w;
        }
        float bb = b0[j];
        #pragma unroll
        for (int r = 0; r < 16; ++r) P0[(n0 + r) * 160 + j] = acc[r] + bb;
    }
}

// ---------------- K6: per-row MLP -> attention scores -------------------------
__global__ void k_mlp(const float* __restrict__ P0, const float* __restrict__ hw0,
                      const float* __restrict__ w1, const float* __restrict__ b1,
                      const float* __restrict__ w2, const float* __restrict__ b2,
                      const float* __restrict__ w3, const float* __restrict__ b3,
                      float* __restrict__ scores)
{
    const int n0 = blockIdx.x * 16;
    const int b  = n0 / MAXN_;      // 16 | 768, so uniform per block
    const int j  = threadIdx.x;     // 192
    __shared__ float bufA[16 * 160];
    __shared__ float bufB[16 * 160];
    __shared__ float red[192];
    // a1 = relu(P0 + hw0[b])
    for (int idx = j; idx < 16 * 160; idx += 192) {
        int r = idx / 160, k = idx - r * 160;
        float v = P0[(n0 + r) * 160 + k] + hw0[b * 160 + k];
        bufA[idx] = v > 0.f ? v : 0.f;
    }
    __syncthreads();
    if (j < 160) {  // a2 = relu(a1@w1+b1)
        float acc[16];
        #pragma unroll
        for (int r = 0; r < 16; ++r) acc[r] = 0.f;
        for (int k = 0; k < 160; ++k) {
            float w = w1[k * 160 + j];
            #pragma unroll
            for (int r = 0; r < 16; ++r) acc[r] += bufA[r * 160 + k] * w;
        }
        float bb = b1[j];
        #pragma unroll
        for (int r = 0; r < 16; ++r) {
            float v = acc[r] + bb;
            bufB[r * 160 + j] = v > 0.f ? v : 0.f;
        }
    }
    __syncthreads();
    if (j < 160) {  // a3 = relu(a2@w2+b2)
        float acc[16];
        #pragma unroll
        for (int r = 0; r < 16; ++r) acc[r] = 0.f;
        for (int k = 0; k < 160; ++k) {
            float w = w2[k * 160 + j];
            #pragma unroll
            for (int r = 0; r < 16; ++r) acc[r] += bufB[r * 160 + k] * w;
        }
        float bb = b2[j];
        #pragma unroll
        for (int r = 0; r < 16; ++r) {
            float v = acc[r] + bb;
            bufA[r * 160 + j] = v > 0.f ? v : 0.f;
        }
    }
    __syncthreads();
    {   // score = a3 . w3 + b3
        int r = j / 12, lane = j - r * 12;   // 16 rows x 12 threads
        float p = 0.f;
        for (int k = lane; k < 160; k += 12) p += bufA[r * 160 + k] * w3[k];
        red[j] = p;
    }
    __syncthreads();
    if (j < 16) {
        float s = 0.f;
        #pragma unroll
        for (int i = 0; i < 12; ++i) s += red[j * 12 + i];
        scores[n0 + j] = s + b3[0];
    }
}

// ---------------- K7: per-graph softmax + t + GRU + hw0_next ------------------
__global__ void k_graph(const float* __restrict__ scores,
                        const float* __restrict__ x, const float* __restrict__ lpe,
                        const float* __restrict__ rwse,
                        const float* __restrict__ Wi, const float* __restrict__ Wh,
                        const float* __restrict__ bi, const float* __restrict__ bh,
                        const float* __restrict__ w0h,
                        float* __restrict__ h, float* __restrict__ hw0,
                        float* __restrict__ tok, int step)
{
    const int b   = blockIdx.x;
    const int tid = threadIdx.x;  // 256
    __shared__ float eL[MAXN_];
    __shared__ float tL[160];
    __shared__ float hL[160];
    __shared__ float hN[160];
    __shared__ float red[8];
    const float inv_sqrt_d = 0.08838834764831845f;  // 128^-0.5

    float m = -1e30f;
    for (int i = tid; i < MAXN_; i += 256) {
        float q = scores[b * MAXN_ + i] * inv_sqrt_d;
        eL[i] = q;
        m = fmaxf(m, q);
    }
    m = blkMax(m, red);
    float s = 0.f;
    for (int i = tid; i < MAXN_; i += 256) {
        float e = __expf(eL[i] - m);
        eL[i] = e;
        s += e;
    }
    if (tid < 160) hL[tid] = h[b * 160 + tid];
    float S = blkSum(s, red);
    float scale = 1.f / (S * (float)MAXN_);
    // t = sum_i alpha_i * xp_i / MAXN
    if (tid < 160) {
        const int c = tid;
        float acc = 0.f;
        for (int i = 0; i < MAXN_; ++i) {
            int n = b * MAXN_ + i;
            float v;
            if (c < 128)      v = x[n * 128 + c];
            else if (c < 144) v = lpe[n * 16 + (c - 128)];
            else              v = rwse[n * 16 + (c - 144)];
            acc += eL[i] * v;
        }
        float tv = acc * scale;
        tL[c] = tv;
        tok[b * 640 + step * 160 + c] = tv;
    }
    __syncthreads();
    // GRU
    if (tid < 160) {
        const int c = tid;
        float gr = bi[c], gz = bi[160 + c], gn = bi[320 + c];
        float hr = bh[c], hz = bh[160 + c], hn = bh[320 + c];
        for (int k = 0; k < 160; ++k) {
            float tv = tL[k], hv = hL[k];
            gr += tv * Wi[k * 480 + c];
            gz += tv * Wi[k * 480 + 160 + c];
            gn += tv * Wi[k * 480 + 320 + c];
            hr += hv * Wh[k * 480 + c];
            hz += hv * Wh[k * 480 + 160 + c];
            hn += hv * Wh[k * 480 + 320 + c];
        }
        float r = sigm(gr + hr);
        float z = sigm(gz + hz);
        float n = tanhf(gn + r * hn);
        float hnew = (1.f - z) * n + z * hL[c];
        hN[c] = hnew;
        h[b * 160 + c] = hnew;
    }
    __syncthreads();
    // hw0_next = h_new @ wm_w0[160:,:]
    if (tid < 160) {
        const int j = tid;
        float acc = 0.f;
        for (int k = 0; k < 160; ++k) acc += hN[k] * w0h[k * 160 + j];
        hw0[b * 160 + j] = acc;
    }
}

// ---------------- K9: mamba-ish part, one block per graph, t=3 output only ----
__global__ void k_mamba(const float* __restrict__ tok,
                        const float* __restrict__ Win, const float* __restrict__ convw,
                        const float* __restrict__ convb,
                        const float* __restrict__ Wx, const float* __restrict__ Wdt,
                        const float* __restrict__ bdt,
                        const float* __restrict__ Alog, const float* __restrict__ Dp,
                        const float* __restrict__ Wout,
                        const float* __restrict__ lng, const float* __restrict__ lnb,
                        float* __restrict__ mo_last)
{
    const int b   = blockIdx.x;
    const int tid = threadIdx.x;  // 256
    __shared__ float tokL[640];
    __shared__ float xpre[1280];
    __shared__ float xmL[1280];
    __shared__ float z3L[320];
    __shared__ float dtrL[40];
    __shared__ float BmL[512];
    __shared__ float Cm3L[128];
    __shared__ float dtL[1280];
    __shared__ float y3L[320];
    __shared__ float moL[160];
    __shared__ float red[8];

    for (int i = tid; i < 640; i += 256) tokL[i] = tok[b * 640 + i];
    __syncthreads();
    // xm_pre = tok @ Win[:, :320] ; z3 = tok[3] @ Win[:, 320:]
    for (int o = tid; o < 1280; o += 256) {
        int t = o / 320, d = o - t * 320;
        float acc = 0.f;
        for (int k = 0; k < 160; ++k) acc += tokL[t * 160 + k] * Win[k * 640 + d];
        xpre[o] = acc;
    }
    for (int d = tid; d < 320; d += 256) {
        float acc = 0.f;
        for (int k = 0; k < 160; ++k) acc += tokL[480 + k] * Win[k * 640 + 320 + d];
        z3L[d] = acc;
    }
    __syncthreads();
    // causal conv + silu
    for (int o = tid; o < 1280; o += 256) {
        int t = o / 320, d = o - t * 320;
        float acc = convb[d];
        #pragma unroll
        for (int k = 0; k < 4; ++k) {
            int tt = t + k - 3;
            if (tt >= 0) acc += xpre[tt * 320 + d] * convw[d * 4 + k];
        }
        xmL[o] = acc * sigm(acc);
    }
    __syncthreads();
    // dbl = xm @ Wx : dtr(4x10), Bm(4x128), Cm(t=3 only, 128)
    for (int o = tid; o < 680; o += 256) {
        int t, col;
        if (o < 40)       { t = o / 10; col = o - t * 10; }
        else if (o < 552) { int i = o - 40; t = i >> 7; col = 10 + (i & 127); }
        else              { t = 3; col = 138 + (o - 552); }
        float acc = 0.f;
        for (int k = 0; k < 320; ++k) acc += xmL[t * 320 + k] * Wx[k * 266 + col];
        if (o < 40)       dtrL[o] = acc;
        else if (o < 552) BmL[o - 40] = acc;
        else              Cm3L[o - 552] = acc;
    }
    __syncthreads();
    // dt = softplus(dtr @ Wdt + bdt)
    for (int o = tid; o < 1280; o += 256) {
        int t = o / 320, d = o - t * 320;
        float acc = bdt[d];
        #pragma unroll
        for (int r = 0; r < 10; ++r) acc += dtrL[t * 10 + r] * Wdt[r * 320 + d];
        dtL[o] = softplusf(acc);
    }
    __syncthreads();
    // scan over T=4, keep only y at t=3; wave w handles dim d, lane handles 2 states
    {
        int w = tid >> 6, lane = tid & 63;
        for (int dbase = 0; dbase < 320; dbase += 4) {
            int d = dbase + w;
            float A0 = -__expf(Alog[d * 128 + lane]);
            float A1 = -__expf(Alog[d * 128 + 64 + lane]);
            float s0 = 0.f, s1 = 0.f;
            #pragma unroll
            for (int t = 0; t < 4; ++t) {
                float dtv = dtL[t * 320 + d];
                float xv  = xmL[t * 320 + d];
                float c0  = dtv * xv;
                s0 = s0 * __expf(dtv * A0) + c0 * BmL[t * 128 + lane];
                s1 = s1 * __expf(dtv * A1) + c0 * BmL[t * 128 + 64 + lane];
            }
            float contrib = s0 * Cm3L[lane] + s1 * Cm3L[64 + lane];
            #pragma unroll
            for (int off = 32; off > 0; off >>= 1) contrib += __shfl_down(contrib, off);
            if (lane == 0) {
                float y  = contrib + Dp[d] * xmL[3 * 320 + d];
                float zz = z3L[d];
                y3L[d] = y * (zz * sigm(zz));
            }
        }
    }
    __syncthreads();
    // mo = LN(y3 @ Wout)
    if (tid < 160) {
        float acc = 0.f;
        for (int d = 0; d < 320; ++d) acc += y3L[d] * Wout[d * 160 + tid];
        moL[tid] = acc;
    }
    float v  = (tid < 160) ? moL[tid] : 0.f;   // moL write is own-thread; blkSum barriers cover others
    float sm = blkSum(v, red);
    float sq = blkSum(v * v, red);
    float mu  = sm / 160.f;
    float var = sq / 160.f - mu * mu;
    if (tid < 160)
        mo_last[b * 160 + tid] = (moL[tid] - mu) * rsqrtf(var + 1e-5f) * lng[tid] + lnb[tid];
}

// ---------------- K10: merge MLP + two LayerNorms -> out ----------------------
__global__ void k_final(const float* __restrict__ x, const float* __restrict__ xs,
                        const int* __restrict__ batch, const float* __restrict__ mo_last,
                        const float* __restrict__ w0, const float* __restrict__ b0,
                        const float* __restrict__ g0, const float* __restrict__ beta0,
                        const float* __restrict__ w1, const float* __restrict__ b1,
                        const float* __restrict__ lng, const float* __restrict__ lnb,
                        float* __restrict__ out)
{
    const int n0 = blockIdx.x * 16;
    const int j  = threadIdx.x;  // 128
    __shared__ float catL[16 * 544];
    __shared__ float hm[16 * 128];
    __shared__ float red[4];
    for (int idx = j; idx < 16 * 544; idx += 128) {
        int r = idx / 544, c = idx - r * 544;
        int n = n0 + r;
        float v;
        if (c < 128)      v = xs[n * 128 + c];
        else if (c < 256) v = xs[N_NODES * 128 + n * 128 + (c - 128)];
        else if (c < 384) v = xs[2 * N_NODES * 128 + n * 128 + (c - 256)];
        else              v = mo_last[batch[n] * 160 + (c - 384)];
        catL[idx] = v;
    }
    __syncthreads();
    float acc[16];
    #pragma unroll
    for (int r = 0; r < 16; ++r) acc[r] = 0.f;
    for (int k = 0; k < 544; ++k) {
        float w = w0[k * 128 + j];
        #pragma unroll
        for (int r = 0; r < 16; ++r) acc[r] += catL[r * 544 + k] * w;
    }
    float b0j = b0[j], g0j = g0[j], be0j = beta0[j];
    #pragma unroll
    for (int r = 0; r < 16; ++r) hm[r * 128 + j] = acc[r] + b0j;
    // hmid = relu(LN(.)) row-wise
    for (int r = 0; r < 16; ++r) {
        float v  = hm[r * 128 + j];         // own element; blkSum barrier orders the rest
        float sm = blkSum(v, red);
        float sq = blkSum(v * v, red);
        float mu  = sm * (1.f / 128.f);
        float var = sq * (1.f / 128.f) - mu * mu;
        float nv = (v - mu) * rsqrtf(var + 1e-5f) * g0j + be0j;
        hm[r * 128 + j] = nv > 0.f ? nv : 0.f;
    }
    __syncthreads();
    float acc2[16];
    #pragma unroll
    for (int r = 0; r < 16; ++r) acc2[r] = 0.f;
    for (int k = 0; k < 128; ++k) {
        float w = w1[k * 128 + j];
        #pragma unroll
        for (int r = 0; r < 16; ++r) acc2[r] += hm[r * 128 + k] * w;
    }
    float b1j = b1[j], lgj = lng[j], lbj = lnb[j];
    for (int r = 0; r < 16; ++r) {
        float v  = acc2[r] + b1j + x[(n0 + r) * 128 + j];
        float sm = blkSum(v, red);
        float sq = blkSum(v * v, red);
        float mu  = sm * (1.f / 128.f);
        float var = sq * (1.f / 128.f) - mu * mu;
        out[(n0 + r) * 128 + j] = (v - mu) * rsqrtf(var + 1e-5f) * lgj + lbj;
    }
}

extern "C" void kernel_launch(void* const* d_in, const int* in_sizes, int n_in,
                              void* d_out, int out_size, void* d_ws, size_t ws_size,
                              hipStream_t stream) {
    const float* x     = (const float*)d_in[0];
    const float* ea    = (const float*)d_in[1];
    const float* lpe   = (const float*)d_in[2];
    const float* rwse  = (const float*)d_in[3];
    const int*   ei    = (const int*)d_in[4];
    const int*   batch = (const int*)d_in[5];
    const float* We    = (const float*)d_in[6];
    const float* be    = (const float*)d_in[7];
    const float* Wx    = (const float*)d_in[8];
    const float* bx    = (const float*)d_in[9];
    const float* w0    = (const float*)d_in[10];
    const float* b0    = (const float*)d_in[11];
    const float* w1    = (const float*)d_in[12];
    const float* b1    = (const float*)d_in[13];
    const float* w2    = (const float*)d_in[14];
    const float* b2    = (const float*)d_in[15];
    const float* w3    = (const float*)d_in[16];
    const float* b3    = (const float*)d_in[17];
    const float* gWi   = (const float*)d_in[18];
    const float* gWh   = (const float*)d_in[19];
    const float* gbi   = (const float*)d_in[20];
    const float* gbh   = (const float*)d_in[21];
    const float* mWin  = (const float*)d_in[22];
    const float* mcw   = (const float*)d_in[23];
    const float* mcb   = (const float*)d_in[24];
    const float* mWx   = (const float*)d_in[25];
    const float* mWdt  = (const float*)d_in[26];
    const float* mbdt  = (const float*)d_in[27];
    const float* mAlog = (const float*)d_in[28];
    const float* mDp   = (const float*)d_in[29];
    const float* mWout = (const float*)d_in[30];
    const float* lnmg  = (const float*)d_in[31];
    const float* lnmb  = (const float*)d_in[32];
    const float* mgw0  = (const float*)d_in[33];
    const float* mgb0  = (const float*)d_in[34];
    const float* mgg0  = (const float*)d_in[35];
    const float* mgbt0 = (const float*)d_in[36];
    const float* mgw1  = (const float*)d_in[37];
    const float* mgb1  = (const float*)d_in[38];
    const float* lng   = (const float*)d_in[39];
    const float* lnb   = (const float*)d_in[40];
    float* out = (float*)d_out;

    float* ws     = (float*)d_ws;
    float* agg    = ws;                     // 3*N*128 = 18,874,368 floats
    float* P0     = agg + 18874368;         // N*160  =  7,864,320
    float* scores = P0 + 7864320;           // N
    float* hbuf   = scores + N_NODES;       // B*160
    float* hw0    = hbuf + 10240;           // B*160
    float* tokb   = hw0 + 10240;            // B*4*160
    float* mo     = tokb + 40960;           // B*160
    int*   cnt    = (int*)(mo + 10240);     // N ints (also cursor source)
    int*   off    = cnt + N_NODES;          // N+1 ints
    int*   cursor = off + N_NODES + 1;      // N ints
    int*   eids   = cursor + N_NODES;       // E ints

    hipMemsetAsync(cnt, 0, (size_t)N_NODES * 4, stream);
    hipMemsetAsync(hbuf, 0, (size_t)20480 * 4, stream);  // h and hw0

    const int* src = ei;
    const int* dstp = ei + NEDGE;

    k_hist<<<NEDGE / 256, 256, 0, stream>>>(dstp, cnt);
    k_scan<<<1, 256, 0, stream>>>(cnt, off, cursor);
    k_scatter<<<NEDGE / 256, 256, 0, stream>>>(dstp, cursor, eids);
    k_agg<<<N_NODES, 128, 0, stream>>>(x, ea, src, off, eids, We, be, agg);

    dim3 g3(N_NODES / 16, 3);
    k_xs<<<g3, 128, 0, stream>>>(x, agg, Wx, bx);
    k_p0<<<N_NODES / 16, 192, 0, stream>>>(x, lpe, rwse, w0, b0, P0);
    for (int t = 0; t < 4; ++t) {
        k_mlp<<<N_NODES / 16, 192, 0, stream>>>(P0, hw0, w1, b1, w2, b2, w3, b3, scores);
        k_graph<<<BGRAPH, 256, 0, stream>>>(scores, x, lpe, rwse, gWi, gWh, gbi, gbh,
                                            w0 + 160 * 160, hbuf, hw0, tokb, t);
    }
    k_mamba<<<BGRAPH, 256, 0, stream>>>(tokb, mWin, mcw, mcb, mWx, mWdt, mbdt,
                                        mAlog, mDp, mWout, lnmg, lnmb, mo);
    k_final<<<N_NODES / 16, 128, 0, stream>>>(x, agg, batch, mo, mgw0, mgb0, mgg0, mgbt0,
                                              mgw1, mgb1, lng, lnb, out);
}

// Round 3
// 1860.386 us; speedup vs baseline: 1.3319x; 1.1113x over previous
//
#include <hip/hip_runtime.h>
#include <math.h>

#define N_NODES 49152
#define BGRAPH  64
#define MAXN_   768
#define NEDGE   491520
#define DD      128
#define CC      160
#define DI_     320
#define DS_     128
#define DTR_    10

__device__ __forceinline__ float sigm(float x) { return 1.f / (1.f + __expf(-x)); }
__device__ __forceinline__ float softplusf(float x) {
    return (x > 20.f) ? x : log1pf(__expf(x));
}

// block-wide sum: all threads get result. blockDim multiple of 64.
__device__ __forceinline__ float blkSum(float v, float* scratch) {
    __syncthreads();
    #pragma unroll
    for (int off = 32; off > 0; off >>= 1) v += __shfl_down(v, off);
    if ((threadIdx.x & 63) == 0) scratch[threadIdx.x >> 6] = v;
    __syncthreads();
    int nw = blockDim.x >> 6;
    float s = 0.f;
    for (int i = 0; i < nw; ++i) s += scratch[i];
    return s;
}

__device__ __forceinline__ float blkMax(float v, float* scratch) {
    __syncthreads();
    #pragma unroll
    for (int off = 32; off > 0; off >>= 1) v = fmaxf(v, __shfl_down(v, off));
    if ((threadIdx.x & 63) == 0) scratch[threadIdx.x >> 6] = v;
    __syncthreads();
    int nw = blockDim.x >> 6;
    float s = scratch[0];
    for (int i = 1; i < nw; ++i) s = fmaxf(s, scratch[i]);
    return s;
}

// ---------------- CSR build: histogram / scan / scatter -----------------------
__global__ void k_hist(const int* __restrict__ dst, int* __restrict__ cnt) {
    int e = blockIdx.x * 256 + threadIdx.x;
    if (e < NEDGE) atomicAdd(&cnt[dst[e]], 1);
}

__global__ void k_scan(const int* __restrict__ cnt, int* __restrict__ off,
                       int* __restrict__ cursor) {
    __shared__ int part[256];
    const int t = threadIdx.x;           // 256 threads, 192 nodes each
    const int base = t * 192;
    int s = 0;
    for (int i = 0; i < 192; ++i) s += cnt[base + i];
    part[t] = s;
    __syncthreads();
    if (t == 0) {
        int run = 0;
        for (int i = 0; i < 256; ++i) { int v = part[i]; part[i] = run; run += v; }
    }
    __syncthreads();
    int run = part[t];
    for (int i = 0; i < 192; ++i) {
        int idx = base + i;
        off[idx] = run;
        cursor[idx] = run;
        run += cnt[idx];
    }
    if (t == 255) off[N_NODES] = run;    // == NEDGE
}

__global__ void k_scatter(const int* __restrict__ dst, int* __restrict__ cursor,
                          int* __restrict__ eids) {
    int e = blockIdx.x * 256 + threadIdx.x;
    if (e < NEDGE) {
        int pos = atomicAdd(&cursor[dst[e]], 1);
        eids[pos] = e;
    }
}

// ---------------- K2': gather-style gated aggregation (no atomics) ------------
__global__ void k_agg(const float* __restrict__ x, const float* __restrict__ ea,
                      const int* __restrict__ src,
                      const int* __restrict__ off, const int* __restrict__ eids,
                      const float* __restrict__ We, const float* __restrict__ be,
                      float* __restrict__ agg)
{
    const int n = blockIdx.x;
    const int d = threadIdx.x;   // 128
    const float w00 = We[d],           w01 = We[128 + d],       bb0 = be[d];
    const float w10 = We[256 + d],     w11 = We[256 + 128 + d], bb1 = be[128 + d];
    const float w20 = We[512 + d],     w21 = We[512 + 128 + d], bb2 = be[256 + d];
    const int beg = off[n], end = off[n + 1];
    float acc0 = 0.f, acc1 = 0.f, acc2 = 0.f;
    for (int i = beg; i < end; ++i) {
        int e = eids[i];
        int s = src[e];
        float ea0 = ea[2 * e], ea1 = ea[2 * e + 1];
        float xv = x[s * DD + d];
        acc0 += xv * sigm(ea0 * w00 + ea1 * w01 + bb0);
        acc1 += xv * sigm(ea0 * w10 + ea1 * w11 + bb1);
        acc2 += xv * sigm(ea0 * w20 + ea1 * w21 + bb2);
    }
    agg[              n * DD + d] = acc0;
    agg[N_NODES * DD + n * DD + d] = acc1;
    agg[2 * N_NODES * DD + n * DD + d] = acc2;
}

// ---------------- K3: xs_i = relu((x+agg_i)@Wx_i + bx_i), in-place over agg ----
__global__ void k_xs(const float* __restrict__ x, float* __restrict__ agg,
                     const float* __restrict__ Wx, const float* __restrict__ bx)
{
    const int i  = blockIdx.y;
    const int n0 = blockIdx.x * 16;
    const int j  = threadIdx.x;  // 128
    __shared__ float inL[16 * 128];
    float* aggi = agg + i * (N_NODES * DD);
    #pragma unroll
    for (int r = 0; r < 16; ++r)
        inL[r * 128 + j] = x[(n0 + r) * DD + j] + aggi[(n0 + r) * DD + j];
    __syncthreads();
    float acc[16];
    #pragma unroll
    for (int r = 0; r < 16; ++r) acc[r] = 0.f;
    const float* W = Wx + i * (DD * DD);
    for (int k = 0; k < 128; ++k) {
        float w = W[k * 128 + j];
        #pragma unroll
        for (int r = 0; r < 16; ++r) acc[r] += inL[r * 128 + k] * w;
    }
    float bb = bx[i * 128 + j];
    #pragma unroll
    for (int r = 0; r < 16; ++r) {
        float v = acc[r] + bb;
        aggi[(n0 + r) * DD + j] = v > 0.f ? v : 0.f;
    }
}

// ---------------- K4: P0 = xp @ wm_w0[:160] + b0  (step-invariant) ------------
__global__ void k_p0(const float* __restrict__ x, const float* __restrict__ lpe,
                     const float* __restrict__ rwse, const float* __restrict__ w0,
                     const float* __restrict__ b0, float* __restrict__ P0)
{
    const int n0 = blockIdx.x * 16;
    const int j  = threadIdx.x;  // 192
    __shared__ float inL[16 * 160];
    for (int idx = j; idx < 16 * 160; idx += 192) {
        int r = idx / 160, k = idx - r * 160;
        int n = n0 + r;
        float v;
        if (k < 128)      v = x[n * 128 + k];
        else if (k < 144) v = lpe[n * 16 + (k - 128)];
        else              v = rwse[n * 16 + (k - 144)];
        inL[idx] = v;
    }
    __syncthreads();
    if (j < 160) {
        float acc[16];
        #pragma unroll
        for (int r = 0; r < 16; ++r) acc[r] = 0.f;
        for (int k = 0; k < 160; ++k) {
            float w = w0[k * 160 + j];
            #pragma unroll
            for (int r = 0; r < 16; ++r) acc[r] += inL[r * 160 + k] * w;
        }
        float bb = b0[j];
        #pragma unroll
        for (int r = 0; r < 16; ++r) P0[(n0 + r) * 160 + j] = acc[r] + bb;
    }
}

// ---------------- K6: per-row MLP -> attention scores -------------------------
__global__ void k_mlp(const float* __restrict__ P0, const float* __restrict__ hw0,
                      const float* __restrict__ w1, const float* __restrict__ b1,
                      const float* __restrict__ w2, const float* __restrict__ b2,
                      const float* __restrict__ w3, const float* __restrict__ b3,
                      float* __restrict__ scores)
{
    const int n0 = blockIdx.x * 16;
    const int b  = n0 / MAXN_;      // 16 | 768, so uniform per block
    const int j  = threadIdx.x;     // 192
    __shared__ float bufA[16 * 160];
    __shared__ float bufB[16 * 160];
    __shared__ float red[192];
    // a1 = relu(P0 + hw0[b])
    for (int idx = j; idx < 16 * 160; idx += 192) {
        int r = idx / 160, k = idx - r * 160;
        float v = P0[(n0 + r) * 160 + k] + hw0[b * 160 + k];
        bufA[idx] = v > 0.f ? v : 0.f;
    }
    __syncthreads();
    if (j < 160) {  // a2 = relu(a1@w1+b1)
        float acc[16];
        #pragma unroll
        for (int r = 0; r < 16; ++r) acc[r] = 0.f;
        for (int k = 0; k < 160; ++k) {
            float w = w1[k * 160 + j];
            #pragma unroll
            for (int r = 0; r < 16; ++r) acc[r] += bufA[r * 160 + k] * w;
        }
        float bb = b1[j];
        #pragma unroll
        for (int r = 0; r < 16; ++r) {
            float v = acc[r] + bb;
            bufB[r * 160 + j] = v > 0.f ? v : 0.f;
        }
    }
    __syncthreads();
    if (j < 160) {  // a3 = relu(a2@w2+b2)
        float acc[16];
        #pragma unroll
        for (int r = 0; r < 16; ++r) acc[r] = 0.f;
        for (int k = 0; k < 160; ++k) {
            float w = w2[k * 160 + j];
            #pragma unroll
            for (int r = 0; r < 16; ++r) acc[r] += bufB[r * 160 + k] * w;
        }
        float bb = b2[j];
        #pragma unroll
        for (int r = 0; r < 16; ++r) {
            float v = acc[r] + bb;
            bufA[r * 160 + j] = v > 0.f ? v : 0.f;
        }
    }
    __syncthreads();
    {   // score = a3 . w3 + b3
        int r = j / 12, lane = j - r * 12;   // 16 rows x 12 threads
        float p = 0.f;
        for (int k = lane; k < 160; k += 12) p += bufA[r * 160 + k] * w3[k];
        red[j] = p;
    }
    __syncthreads();
    if (j < 16) {
        float s = 0.f;
        #pragma unroll
        for (int i = 0; i < 12; ++i) s += red[j * 12 + i];
        scores[n0 + j] = s + b3[0];
    }
}

// ---------------- K7: per-graph softmax + t + GRU + hw0_next ------------------
__global__ void k_graph(const float* __restrict__ scores,
                        const float* __restrict__ x, const float* __restrict__ lpe,
                        const float* __restrict__ rwse,
                        const float* __restrict__ Wi, const float* __restrict__ Wh,
                        const float* __restrict__ bi, const float* __restrict__ bh,
                        const float* __restrict__ w0h,
                        float* __restrict__ h, float* __restrict__ hw0,
                        float* __restrict__ tok, int step)
{
    const int b   = blockIdx.x;
    const int tid = threadIdx.x;  // 256
    __shared__ float eL[MAXN_];
    __shared__ float tL[160];
    __shared__ float hL[160];
    __shared__ float hN[160];
    __shared__ float red[8];
    const float inv_sqrt_d = 0.08838834764831845f;  // 128^-0.5

    float m = -1e30f;
    for (int i = tid; i < MAXN_; i += 256) {
        float q = scores[b * MAXN_ + i] * inv_sqrt_d;
        eL[i] = q;
        m = fmaxf(m, q);
    }
    m = blkMax(m, red);
    float s = 0.f;
    for (int i = tid; i < MAXN_; i += 256) {
        float e = __expf(eL[i] - m);
        eL[i] = e;
        s += e;
    }
    if (tid < 160) hL[tid] = h[b * 160 + tid];
    float S = blkSum(s, red);
    float scale = 1.f / (S * (float)MAXN_);
    // t = sum_i alpha_i * xp_i / MAXN
    if (tid < 160) {
        const int c = tid;
        float acc = 0.f;
        for (int i = 0; i < MAXN_; ++i) {
            int n = b * MAXN_ + i;
            float v;
            if (c < 128)      v = x[n * 128 + c];
            else if (c < 144) v = lpe[n * 16 + (c - 128)];
            else              v = rwse[n * 16 + (c - 144)];
            acc += eL[i] * v;
        }
        float tv = acc * scale;
        tL[c] = tv;
        tok[b * 640 + step * 160 + c] = tv;
    }
    __syncthreads();
    // GRU
    if (tid < 160) {
        const int c = tid;
        float gr = bi[c], gz = bi[160 + c], gn = bi[320 + c];
        float hr = bh[c], hz = bh[160 + c], hn = bh[320 + c];
        for (int k = 0; k < 160; ++k) {
            float tv = tL[k], hv = hL[k];
            gr += tv * Wi[k * 480 + c];
            gz += tv * Wi[k * 480 + 160 + c];
            gn += tv * Wi[k * 480 + 320 + c];
            hr += hv * Wh[k * 480 + c];
            hz += hv * Wh[k * 480 + 160 + c];
            hn += hv * Wh[k * 480 + 320 + c];
        }
        float r = sigm(gr + hr);
        float z = sigm(gz + hz);
        float n = tanhf(gn + r * hn);
        float hnew = (1.f - z) * n + z * hL[c];
        hN[c] = hnew;
        h[b * 160 + c] = hnew;
    }
    __syncthreads();
    // hw0_next = h_new @ wm_w0[160:,:]
    if (tid < 160) {
        const int j = tid;
        float acc = 0.f;
        for (int k = 0; k < 160; ++k) acc += hN[k] * w0h[k * 160 + j];
        hw0[b * 160 + j] = acc;
    }
}

// ---------------- K9: mamba-ish part, one block per graph, t=3 output only ----
__global__ void k_mamba(const float* __restrict__ tok,
                        const float* __restrict__ Win, const float* __restrict__ convw,
                        const float* __restrict__ convb,
                        const float* __restrict__ Wx, const float* __restrict__ Wdt,
                        const float* __restrict__ bdt,
                        const float* __restrict__ Alog, const float* __restrict__ Dp,
                        const float* __restrict__ Wout,
                        const float* __restrict__ lng, const float* __restrict__ lnb,
                        float* __restrict__ mo_last)
{
    const int b   = blockIdx.x;
    const int tid = threadIdx.x;  // 256
    __shared__ float tokL[640];
    __shared__ float xpre[1280];
    __shared__ float xmL[1280];
    __shared__ float z3L[320];
    __shared__ float dtrL[40];
    __shared__ float BmL[512];
    __shared__ float Cm3L[128];
    __shared__ float dtL[1280];
    __shared__ float y3L[320];
    __shared__ float moL[160];
    __shared__ float red[8];

    for (int i = tid; i < 640; i += 256) tokL[i] = tok[b * 640 + i];
    __syncthreads();
    // xm_pre = tok @ Win[:, :320] ; z3 = tok[3] @ Win[:, 320:]
    for (int o = tid; o < 1280; o += 256) {
        int t = o / 320, d = o - t * 320;
        float acc = 0.f;
        for (int k = 0; k < 160; ++k) acc += tokL[t * 160 + k] * Win[k * 640 + d];
        xpre[o] = acc;
    }
    for (int d = tid; d < 320; d += 256) {
        float acc = 0.f;
        for (int k = 0; k < 160; ++k) acc += tokL[480 + k] * Win[k * 640 + 320 + d];
        z3L[d] = acc;
    }
    __syncthreads();
    // causal conv + silu
    for (int o = tid; o < 1280; o += 256) {
        int t = o / 320, d = o - t * 320;
        float acc = convb[d];
        #pragma unroll
        for (int k = 0; k < 4; ++k) {
            int tt = t + k - 3;
            if (tt >= 0) acc += xpre[tt * 320 + d] * convw[d * 4 + k];
        }
        xmL[o] = acc * sigm(acc);
    }
    __syncthreads();
    // dbl = xm @ Wx : dtr(4x10), Bm(4x128), Cm(t=3 only, 128)
    for (int o = tid; o < 680; o += 256) {
        int t, col;
        if (o < 40)       { t = o / 10; col = o - t * 10; }
        else if (o < 552) { int i = o - 40; t = i >> 7; col = 10 + (i & 127); }
        else              { t = 3; col = 138 + (o - 552); }
        float acc = 0.f;
        for (int k = 0; k < 320; ++k) acc += xmL[t * 320 + k] * Wx[k * 266 + col];
        if (o < 40)       dtrL[o] = acc;
        else if (o < 552) BmL[o - 40] = acc;
        else              Cm3L[o - 552] = acc;
    }
    __syncthreads();
    // dt = softplus(dtr @ Wdt + bdt)
    for (int o = tid; o < 1280; o += 256) {
        int t = o / 320, d = o - t * 320;
        float acc = bdt[d];
        #pragma unroll
        for (int r = 0; r < 10; ++r) acc += dtrL[t * 10 + r] * Wdt[r * 320 + d];
        dtL[o] = softplusf(acc);
    }
    __syncthreads();
    // scan over T=4, keep only y at t=3; wave w handles dim d, lane handles 2 states
    {
        int w = tid >> 6, lane = tid & 63;
        for (int dbase = 0; dbase < 320; dbase += 4) {
            int d = dbase + w;
            float A0 = -__expf(Alog[d * 128 + lane]);
            float A1 = -__expf(Alog[d * 128 + 64 + lane]);
            float s0 = 0.f, s1 = 0.f;
            #pragma unroll
            for (int t = 0; t < 4; ++t) {
                float dtv = dtL[t * 320 + d];
                float xv  = xmL[t * 320 + d];
                float c0  = dtv * xv;
                s0 = s0 * __expf(dtv * A0) + c0 * BmL[t * 128 + lane];
                s1 = s1 * __expf(dtv * A1) + c0 * BmL[t * 128 + 64 + lane];
            }
            float contrib = s0 * Cm3L[lane] + s1 * Cm3L[64 + lane];
            #pragma unroll
            for (int off = 32; off > 0; off >>= 1) contrib += __shfl_down(contrib, off);
            if (lane == 0) {
                float y  = contrib + Dp[d] * xmL[3 * 320 + d];
                float zz = z3L[d];
                y3L[d] = y * (zz * sigm(zz));
            }
        }
    }
    __syncthreads();
    // mo = LN(y3 @ Wout)
    if (tid < 160) {
        float acc = 0.f;
        for (int d = 0; d < 320; ++d) acc += y3L[d] * Wout[d * 160 + tid];
        moL[tid] = acc;
    }
    float v  = (tid < 160) ? moL[tid] : 0.f;   // moL write is own-thread; blkSum barriers cover others
    float sm = blkSum(v, red);
    float sq = blkSum(v * v, red);
    float mu  = sm / 160.f;
    float var = sq / 160.f - mu * mu;
    if (tid < 160)
        mo_last[b * 160 + tid] = (moL[tid] - mu) * rsqrtf(var + 1e-5f) * lng[tid] + lnb[tid];
}

// ---------------- K10: merge MLP + two LayerNorms -> out ----------------------
// Single wave per 8-row tile. Thread = (slice s = tid>>4, colgroup cg = tid&15).
// Each thread: 8 rows x 8 cols register tile; K split across 4 slices interleaved
// (k = 4t+s). Cross-slice reduce via shfl_xor(16,32); row LN stats via in-lane
// sum + shfl_xor(1,2,4,8). Zero blkSum barriers.
__global__ __launch_bounds__(64) void k_final(
        const float* __restrict__ x, const float* __restrict__ xs,
        const int* __restrict__ batch, const float* __restrict__ mo_last,
        const float* __restrict__ w0, const float* __restrict__ b0,
        const float* __restrict__ g0, const float* __restrict__ beta0,
        const float* __restrict__ w1, const float* __restrict__ b1,
        const float* __restrict__ lng, const float* __restrict__ lnb,
        float* __restrict__ out)
{
    const int n0  = blockIdx.x * 8;
    const int tid = threadIdx.x;     // 64
    const int cg  = tid & 15;
    const int s   = tid >> 4;
    const int j0  = cg * 8;
    __shared__ float catT[544 * 8];  // [k][r]
    __shared__ float hmR[8 * 128];   // [r][k]

    // stage catT[k*8+r] = cat[row n0+r][col k]
    for (int idx = tid; idx < 544 * 8; idx += 64) {
        int r = idx & 7, k = idx >> 3;
        int n = n0 + r;
        float v;
        if (k < 384) v = xs[(k >> 7) * (N_NODES * 128) + n * 128 + (k & 127)];
        else         v = mo_last[batch[n] * 160 + (k - 384)];
        catT[idx] = v;
    }
    __syncthreads();

    // ---- GEMM1: acc[r][c] = sum_k cat[r][k] * w0[k][j0+c] ----
    float acc[8][8];
    #pragma unroll
    for (int r = 0; r < 8; ++r)
        #pragma unroll
        for (int c = 0; c < 8; ++c) acc[r][c] = 0.f;
    for (int t = 0; t < 136; ++t) {
        int k = 4 * t + s;
        float4 ca = *(const float4*)&catT[k * 8];
        float4 cb = *(const float4*)&catT[k * 8 + 4];
        float4 wa = *(const float4*)&w0[k * 128 + j0];
        float4 wb = *(const float4*)&w0[k * 128 + j0 + 4];
        float cr[8] = {ca.x, ca.y, ca.z, ca.w, cb.x, cb.y, cb.z, cb.w};
        float wr[8] = {wa.x, wa.y, wa.z, wa.w, wb.x, wb.y, wb.z, wb.w};
        #pragma unroll
        for (int r = 0; r < 8; ++r)
            #pragma unroll
            for (int c = 0; c < 8; ++c) acc[r][c] += cr[r] * wr[c];
    }
    // reduce across slices (lane bits 4,5)
    #pragma unroll
    for (int m = 16; m <= 32; m <<= 1)
        #pragma unroll
        for (int r = 0; r < 8; ++r)
            #pragma unroll
            for (int c = 0; c < 8; ++c) acc[r][c] += __shfl_xor(acc[r][c], m);

    // ---- LN1 + relu (per row over 128 cols) ----
    {
        float4 ba  = *(const float4*)&b0[j0],    bb4 = *(const float4*)&b0[j0 + 4];
        float4 ga  = *(const float4*)&g0[j0],    gb  = *(const float4*)&g0[j0 + 4];
        float4 ta  = *(const float4*)&beta0[j0], tb  = *(const float4*)&beta0[j0 + 4];
        float bs[8] = {ba.x, ba.y, ba.z, ba.w, bb4.x, bb4.y, bb4.z, bb4.w};
        float gg[8] = {ga.x, ga.y, ga.z, ga.w, gb.x, gb.y, gb.z, gb.w};
        float bt[8] = {ta.x, ta.y, ta.z, ta.w, tb.x, tb.y, tb.z, tb.w};
        float rs[8], rq[8];
        #pragma unroll
        for (int r = 0; r < 8; ++r) {
            float sm = 0.f, sq = 0.f;
            #pragma unroll
            for (int c = 0; c < 8; ++c) {
                float v = acc[r][c] + bs[c];
                acc[r][c] = v;
                sm += v; sq += v * v;
            }
            rs[r] = sm; rq[r] = sq;
        }
        #pragma unroll
        for (int m = 1; m <= 8; m <<= 1)
            #pragma unroll
            for (int r = 0; r < 8; ++r) {
                rs[r] += __shfl_xor(rs[r], m);
                rq[r] += __shfl_xor(rq[r], m);
            }
        #pragma unroll
        for (int r = 0; r < 8; ++r) {
            float mu = rs[r] * (1.f / 128.f);
            float var = rq[r] * (1.f / 128.f) - mu * mu;
            float rv = rsqrtf(var + 1e-5f);
            #pragma unroll
            for (int c = 0; c < 8; ++c) {
                float nv = (acc[r][c] - mu) * rv * gg[c] + bt[c];
                acc[r][c] = nv > 0.f ? nv : 0.f;
            }
        }
    }
    // slice s writes rows 2s, 2s+1 of hmR
    #pragma unroll
    for (int rr = 0; rr < 2; ++rr) {
        int r = 2 * s + rr;
        *(float4*)&hmR[r * 128 + j0]     = make_float4(acc[r][0], acc[r][1], acc[r][2], acc[r][3]);
        *(float4*)&hmR[r * 128 + j0 + 4] = make_float4(acc[r][4], acc[r][5], acc[r][6], acc[r][7]);
    }
    __syncthreads();

    // ---- GEMM2: acc2[r][c] = sum_k hm[r][k] * w1[k][j0+c] ----
    float acc2[8][8];
    #pragma unroll
    for (int r = 0; r < 8; ++r)
        #pragma unroll
        for (int c = 0; c < 8; ++c) acc2[r][c] = 0.f;
    for (int t = 0; t < 32; ++t) {
        int k = 4 * t + s;
        float hr[8];
        #pragma unroll
        for (int r = 0; r < 8; ++r) hr[r] = hmR[r * 128 + k];
        float4 wa = *(const float4*)&w1[k * 128 + j0];
        float4 wb = *(const float4*)&w1[k * 128 + j0 + 4];
        float wr[8] = {wa.x, wa.y, wa.z, wa.w, wb.x, wb.y, wb.z, wb.w};
        #pragma unroll
        for (int r = 0; r < 8; ++r)
            #pragma unroll
            for (int c = 0; c < 8; ++c) acc2[r][c] += hr[r] * wr[c];
    }
    #pragma unroll
    for (int m = 16; m <= 32; m <<= 1)
        #pragma unroll
        for (int r = 0; r < 8; ++r)
            #pragma unroll
            for (int c = 0; c < 8; ++c) acc2[r][c] += __shfl_xor(acc2[r][c], m);

    // ---- residual + LN2 + store ----
    {
        float4 ba = *(const float4*)&b1[j0],  bb4 = *(const float4*)&b1[j0 + 4];
        float4 ga = *(const float4*)&lng[j0], gb  = *(const float4*)&lng[j0 + 4];
        float4 ta = *(const float4*)&lnb[j0], tb  = *(const float4*)&lnb[j0 + 4];
        float bs[8] = {ba.x, ba.y, ba.z, ba.w, bb4.x, bb4.y, bb4.z, bb4.w};
        float gg[8] = {ga.x, ga.y, ga.z, ga.w, gb.x, gb.y, gb.z, gb.w};
        float bt[8] = {ta.x, ta.y, ta.z, ta.w, tb.x, tb.y, tb.z, tb.w};
        float rs[8], rq[8];
        #pragma unroll
        for (int r = 0; r < 8; ++r) {
            float4 xa = *(const float4*)&x[(n0 + r) * 128 + j0];
            float4 xb = *(const float4*)&x[(n0 + r) * 128 + j0 + 4];
            float xr[8] = {xa.x, xa.y, xa.z, xa.w, xb.x, xb.y, xb.z, xb.w};
            float sm = 0.f, sq = 0.f;
            #pragma unroll
            for (int c = 0; c < 8; ++c) {
                float v = acc2[r][c] + bs[c] + xr[c];
                acc2[r][c] = v;
                sm += v; sq += v * v;
            }
            rs[r] = sm; rq[r] = sq;
        }
        #pragma unroll
        for (int m = 1; m <= 8; m <<= 1)
            #pragma unroll
            for (int r = 0; r < 8; ++r) {
                rs[r] += __shfl_xor(rs[r], m);
                rq[r] += __shfl_xor(rq[r], m);
            }
        #pragma unroll
        for (int r = 0; r < 8; ++r) {
            float mu = rs[r] * (1.f / 128.f);
            float var = rq[r] * (1.f / 128.f) - mu * mu;
            float rv = rsqrtf(var + 1e-5f);
            #pragma unroll
            for (int c = 0; c < 8; ++c)
                acc2[r][c] = (acc2[r][c] - mu) * rv * gg[c] + bt[c];
        }
        // slice s stores rows 2s, 2s+1
        #pragma unroll
        for (int rr = 0; rr < 2; ++rr) {
            int r = 2 * s + rr;
            *(float4*)&out[(n0 + r) * 128 + j0] =
                make_float4(acc2[r][0], acc2[r][1], acc2[r][2], acc2[r][3]);
            *(float4*)&out[(n0 + r) * 128 + j0 + 4] =
                make_float4(acc2[r][4], acc2[r][5], acc2[r][6], acc2[r][7]);
        }
    }
}

extern "C" void kernel_launch(void* const* d_in, const int* in_sizes, int n_in,
                              void* d_out, int out_size, void* d_ws, size_t ws_size,
                              hipStream_t stream) {
    const float* x     = (const float*)d_in[0];
    const float* ea    = (const float*)d_in[1];
    const float* lpe   = (const float*)d_in[2];
    const float* rwse  = (const float*)d_in[3];
    const int*   ei    = (const int*)d_in[4];
    const int*   batch = (const int*)d_in[5];
    const float* We    = (const float*)d_in[6];
    const float* be    = (const float*)d_in[7];
    const float* Wx    = (const float*)d_in[8];
    const float* bx    = (const float*)d_in[9];
    const float* w0    = (const float*)d_in[10];
    const float* b0    = (const float*)d_in[11];
    const float* w1    = (const float*)d_in[12];
    const float* b1    = (const float*)d_in[13];
    const float* w2    = (const float*)d_in[14];
    const float* b2    = (const float*)d_in[15];
    const float* w3    = (const float*)d_in[16];
    const float* b3    = (const float*)d_in[17];
    const float* gWi   = (const float*)d_in[18];
    const float* gWh   = (const float*)d_in[19];
    const float* gbi   = (const float*)d_in[20];
    const float* gbh   = (const float*)d_in[21];
    const float* mWin  = (const float*)d_in[22];
    const float* mcw   = (const float*)d_in[23];
    const float* mcb   = (const float*)d_in[24];
    const float* mWx   = (const float*)d_in[25];
    const float* mWdt  = (const float*)d_in[26];
    const float* mbdt  = (const float*)d_in[27];
    const float* mAlog = (const float*)d_in[28];
    const float* mDp   = (const float*)d_in[29];
    const float* mWout = (const float*)d_in[30];
    const float* lnmg  = (const float*)d_in[31];
    const float* lnmb  = (const float*)d_in[32];
    const float* mgw0  = (const float*)d_in[33];
    const float* mgb0  = (const float*)d_in[34];
    const float* mgg0  = (const float*)d_in[35];
    const float* mgbt0 = (const float*)d_in[36];
    const float* mgw1  = (const float*)d_in[37];
    const float* mgb1  = (const float*)d_in[38];
    const float* lng   = (const float*)d_in[39];
    const float* lnb   = (const float*)d_in[40];
    float* out = (float*)d_out;

    float* ws     = (float*)d_ws;
    float* agg    = ws;                     // 3*N*128 = 18,874,368 floats
    float* P0     = agg + 18874368;         // N*160  =  7,864,320
    float* scores = P0 + 7864320;           // N
    float* hbuf   = scores + N_NODES;       // B*160
    float* hw0    = hbuf + 10240;           // B*160
    float* tokb   = hw0 + 10240;            // B*4*160
    float* mo     = tokb + 40960;           // B*160
    int*   cnt    = (int*)(mo + 10240);     // N ints (also cursor source)
    int*   off    = cnt + N_NODES;          // N+1 ints
    int*   cursor = off + N_NODES + 1;      // N ints
    int*   eids   = cursor + N_NODES;       // E ints

    hipMemsetAsync(cnt, 0, (size_t)N_NODES * 4, stream);
    hipMemsetAsync(hbuf, 0, (size_t)20480 * 4, stream);  // h and hw0

    const int* src = ei;
    const int* dstp = ei + NEDGE;

    k_hist<<<NEDGE / 256, 256, 0, stream>>>(dstp, cnt);
    k_scan<<<1, 256, 0, stream>>>(cnt, off, cursor);
    k_scatter<<<NEDGE / 256, 256, 0, stream>>>(dstp, cursor, eids);
    k_agg<<<N_NODES, 128, 0, stream>>>(x, ea, src, off, eids, We, be, agg);

    dim3 g3(N_NODES / 16, 3);
    k_xs<<<g3, 128, 0, stream>>>(x, agg, Wx, bx);
    k_p0<<<N_NODES / 16, 192, 0, stream>>>(x, lpe, rwse, w0, b0, P0);
    for (int t = 0; t < 4; ++t) {
        k_mlp<<<N_NODES / 16, 192, 0, stream>>>(P0, hw0, w1, b1, w2, b2, w3, b3, scores);
        k_graph<<<BGRAPH, 256, 0, stream>>>(scores, x, lpe, rwse, gWi, gWh, gbi, gbh,
                                            w0 + 160 * 160, hbuf, hw0, tokb, t);
    }
    k_mamba<<<BGRAPH, 256, 0, stream>>>(tokb, mWin, mcw, mcb, mWx, mWdt, mbdt,
                                        mAlog, mDp, mWout, lnmg, lnmb, mo);
    k_final<<<N_NODES / 8, 64, 0, stream>>>(x, agg, batch, mo, mgw0, mgb0, mgg0, mgbt0,
                                            mgw1, mgb1, lng, lnb, out);
}